// Round 17
// baseline (51.337 us; speedup 1.0000x reference)
//
#include <hip/hip_runtime.h>
#include <hip/hip_bf16.h>

#define N_ROWS 8192
#define DIM 128
#define MARGIN_F 0.3f

typedef __attribute__((ext_vector_type(8))) short short8;
typedef __attribute__((ext_vector_type(4))) float f32x4;

typedef const void __attribute__((address_space(1)))* gas1_t;
typedef void __attribute__((address_space(3)))* las3_t;

__device__ __forceinline__ void load_lds16(const void* g, void* l) {
  __builtin_amdgcn_global_load_lds((gas1_t)g, (las3_t)l, 16, 0, 0);
}

// ---------------- Kernel A: fp32 -> bf16 (two layouts), norms, init --------
// xbA: fragment-major (-2x): 16B unit u = c16*256 + kk*64 + l4*16 + l15 holds
//   elems [kk*32+l4*8..+8) of row (c16*16+l15); panel load = xfA[c16*256 +
//   kk*64 + lane] (64 lanes contiguous). -2x is an exact pow2 scale; seeding
//   the MFMA accumulator with sqc then yields v = sqc - 2*s directly.
// xbBrow: row-major (x), 256 B/row, source for swizzled global_load_lds.
__global__ __launch_bounds__(256) void prep_kernel(
    const float* __restrict__ x, const int* __restrict__ tgt,
    unsigned short* __restrict__ xbA, unsigned short* __restrict__ xbBrow,
    float2* __restrict__ meta, int* __restrict__ apb, int* __restrict__ anb,
    unsigned long long* __restrict__ lsum, unsigned int* __restrict__ lcnt) {
  if (blockIdx.x == 0 && threadIdx.x == 0) { *lsum = 0ull; *lcnt = 0u; }
  const int w = threadIdx.x >> 6, l = threadIdx.x & 63;
  const int row = blockIdx.x * 4 + w;
  float2 v = reinterpret_cast<const float2*>(x + (size_t)row * DIM)[l];
  __hip_bfloat16 b0 = __float2bfloat16(v.x);
  __hip_bfloat16 b1 = __float2bfloat16(v.y);
  __hip_bfloat16 a0 = __float2bfloat16(-2.f * v.x);
  __hip_bfloat16 a1 = __float2bfloat16(-2.f * v.y);
  ushort2 stB, stA;
  stB.x = *reinterpret_cast<unsigned short*>(&b0);
  stB.y = *reinterpret_cast<unsigned short*>(&b1);
  stA.x = *reinterpret_cast<unsigned short*>(&a0);
  stA.y = *reinterpret_cast<unsigned short*>(&a1);
  reinterpret_cast<ushort2*>(xbBrow)[(size_t)row * 64 + l] = stB;
  const int c16 = row >> 4, l15r = row & 15;
  const int unit = c16 * 256 + (l >> 4) * 64 + ((l >> 2) & 3) * 16 + l15r;
  reinterpret_cast<ushort2*>(xbA)[unit * 4 + (l & 3)] = stA;

  float s = v.x * v.x + v.y * v.y;
  #pragma unroll
  for (int off = 32; off >= 1; off >>= 1) s += __shfl_xor(s, off);
  if (l == 0) {
    float2 m;
    m.x = s;
    m.y = __int_as_float(tgt[row]);   // raw bit carry; only ever bit-compared
    meta[row] = m;
    apb[row] = 0x00000000;            // 0.0f (max identity; diagonal is positive)
    anb[row] = 0x7f800000;            // +inf (min identity)
  }
}

// ---------------- Kernel B: m97-structure Gram + mining --------------------
// grid (64,8) = 512 blocks = 2/CU exactly. Block = 4 waves in a 2x2 grid:
// wave output = 64 rows x 64 cols (4x4 16x16 fragments = 16 independent MFMA
// chains, 310-cyc reissue spacing). Block tile = 128 rows x 128 cols/slice,
// 8 slices of 128 cols (1024-col chunk). B staged once per block per slice
// (32 KB) via global_load_lds, XOR-swizzled, ping-pong 2 buffers, COUNTED
// vmcnt(8) (never full drain mid-loop) + two raw barriers per slice (first:
// buffer ready; second: all readers done before the parity buffer is
// re-staged). Column meta in LDS (Ms) so the steady-state vmcnt queue holds
// stage loads only. Totals: global B traffic 64 MB (was 512 MB streaming),
// LDS-read 256 MB (3.7us), MFMA floor 8.3us, VALU ~5us.
__global__ __launch_bounds__(256, 2) void gram_mine_kernel(
    const unsigned short* __restrict__ xbA, const unsigned short* __restrict__ xbBrow,
    const float2* __restrict__ meta, int* __restrict__ apb, int* __restrict__ anb) {
  __shared__ unsigned short Bs[2][128 * 128];   // 2 x 32 KB ping-pong
  __shared__ float2 Ms[1024];                   // 8 KB column (sq, class)

  const int t = threadIdx.x;
  const int w = t >> 6, l = t & 63;
  const int l15 = l & 15, l4 = l >> 4;
  const int wr = w >> 1, wc = w & 1;
  const int rb = blockIdx.x * 128 + wr * 64;    // wave's global row base
  const int chunk = blockIdx.y * 1024;          // block's 1024-col chunk

  // ---- prologue staging FIRST so slice-0's vmcnt(8) drains everything old:
  // Ms (2 loads) + stage slice 0 (8 loads); A/t_r loads issue after and are
  // also older than stage(1), so vmcnt(8) at slice 0 retires them all.
  {
    #pragma unroll
    for (int r = 0; r < 2; ++r) {
      int c = r * 256 + t;                      // 512 x 16B = 8 KB meta
      load_lds16(reinterpret_cast<const char*>(meta + chunk) + c * 16,
                 (char*)(&Ms[0]) + c * 16);
    }
    #pragma unroll
    for (int r = 0; r < 8; ++r) {               // slice 0 -> Bs[0]
      int c = r * 256 + t;                      // 2048 x 16B = 32 KB
      int col_local = c >> 4;
      int off = ((c & 15) * 16) ^ ((col_local & 7) << 4);
      const char* src = reinterpret_cast<const char*>(xbBrow) +
                        (size_t)(chunk + col_local) * 256 + off;
      load_lds16(src, (char*)(&Bs[0][0]) + c * 16);
    }
  }

  const short8* xfA = reinterpret_cast<const short8*>(xbA);

  // A fragments (-2x): panels (rb>>4)+rf, rf=0..3 (rows rb..rb+63), 64 VGPR
  short8 a[4][4];
  #pragma unroll
  for (int rf = 0; rf < 4; ++rf)
    #pragma unroll
    for (int kk = 0; kk < 4; ++kk)
      a[rf][kk] = xfA[((rb >> 4) + rf) * 256 + kk * 64 + l];

  // per-lane row classes (C/D layout rows: rb + rf*16 + l4*4 + rg)
  int t_r[16];
  #pragma unroll
  for (int rf = 0; rf < 4; ++rf)
    #pragma unroll
    for (int rg = 0; rg < 4; ++rg)
      t_r[rf * 4 + rg] = __float_as_int(meta[rb + rf * 16 + l4 * 4 + rg].y);

  // mining state on v = sqc - 2*s (row term +sq_r deferred to the end)
  float ap2[16], an2[16];
  #pragma unroll
  for (int i = 0; i < 16; ++i) { ap2[i] = -__builtin_inff(); an2[i] = __builtin_inff(); }

  #pragma unroll 1
  for (int s = 0; s < 8; ++s) {
    // stage slice s+1 into the other parity buffer (readers of that buffer
    // finished at slice (s-1)'s end-barrier)
    if (s < 7) {
      const int colbase = chunk + (s + 1) * 128;
      #pragma unroll
      for (int r = 0; r < 8; ++r) {
        int c = r * 256 + t;
        int col_local = c >> 4;
        int off = ((c & 15) * 16) ^ ((col_local & 7) << 4);
        const char* src = reinterpret_cast<const char*>(xbBrow) +
                          (size_t)(colbase + col_local) * 256 + off;
        load_lds16(src, (char*)(&Bs[(s + 1) & 1][0]) + c * 16);
      }
      __builtin_amdgcn_sched_barrier(0);
      asm volatile("s_waitcnt vmcnt(8)" ::: "memory");  // slice s landed; s+1 in flight
    } else {
      __builtin_amdgcn_sched_barrier(0);
      asm volatile("s_waitcnt vmcnt(0)" ::: "memory");
    }
    __builtin_amdgcn_s_barrier();                       // Bs[s&1] ready for all
    __builtin_amdgcn_sched_barrier(0);

    // column meta for this wave's 64 cols (ds_read; vmcnt queue untouched)
    float2 mc[4];
    #pragma unroll
    for (int cf = 0; cf < 4; ++cf)
      mc[cf] = Ms[s * 128 + wc * 64 + cf * 16 + l15];

    // acc seeded with sqc: MFMA (-2x A) emits v = sqc - 2s directly
    f32x4 acc[4][4];
    #pragma unroll
    for (int cf = 0; cf < 4; ++cf) {
      f32x4 ci = {mc[cf].x, mc[cf].x, mc[cf].x, mc[cf].x};
      #pragma unroll
      for (int rf = 0; rf < 4; ++rf) acc[rf][cf] = ci;
    }

    __builtin_amdgcn_s_setprio(1);
    const char* bbase = reinterpret_cast<const char*>(&Bs[s & 1][0]);
    #pragma unroll
    for (int kk = 0; kk < 4; ++kk) {
      short8 bfr[4];
      #pragma unroll
      for (int cf = 0; cf < 4; ++cf) {
        int col_local = wc * 64 + cf * 16 + l15;
        int kb = (kk * 64 + l4 * 16) ^ ((col_local & 7) << 4);
        bfr[cf] = *reinterpret_cast<const short8*>(bbase + col_local * 256 + kb);
      }
      #pragma unroll
      for (int cf = 0; cf < 4; ++cf)
        #pragma unroll
        for (int rf = 0; rf < 4; ++rf)
          acc[rf][cf] = __builtin_amdgcn_mfma_f32_16x16x32_bf16(
              a[rf][kk], bfr[cf], acc[rf][cf], 0, 0, 0);
    }
    __builtin_amdgcn_s_setprio(0);

    // mining epilogue (16 fragments x 4 elems x ~5 VALU)
    #pragma unroll
    for (int cf = 0; cf < 4; ++cf) {
      const int tc = __float_as_int(mc[cf].y);
      #pragma unroll
      for (int rf = 0; rf < 4; ++rf)
        #pragma unroll
        for (int rg = 0; rg < 4; ++rg) {
          const int ix = rf * 4 + rg;
          float v = acc[rf][cf][rg];
          bool p = (t_r[ix] == tc);
          ap2[ix] = p ? fmaxf(ap2[ix], v) : ap2[ix];
          an2[ix] = p ? an2[ix] : fminf(an2[ix], v);
        }
    }

    // end barrier: all readers of Bs[s&1] done before it is re-staged (s+2)
    if (s < 7) __builtin_amdgcn_s_barrier();
  }

  // reduce across the 16 lanes (same l4 group = same rows, different cols)
  #pragma unroll
  for (int i = 0; i < 16; ++i) {
    #pragma unroll
    for (int off = 1; off < 16; off <<= 1) {
      ap2[i] = fmaxf(ap2[i], __shfl_xor(ap2[i], off));
      an2[i] = fminf(an2[i], __shfl_xor(an2[i], off));
    }
  }
  if (l15 == 0) {
    #pragma unroll
    for (int rf = 0; rf < 4; ++rf)
      #pragma unroll
      for (int rg = 0; rg < 4; ++rg) {
        int row = rb + rf * 16 + l4 * 4 + rg;
        float sqr = meta[row].x;
        // d^2 = v + sq_r; clamp >=1e-12 commutes with max/min; non-negative
        // floats are int-monotone -> int atomics give exact fp max/min.
        float a2 = fmaxf(ap2[rf * 4 + rg] + sqr, 1e-12f);
        float n2 = fmaxf(an2[rf * 4 + rg] + sqr, 1e-12f);
        atomicMax(apb + row, __float_as_int(a2));
        atomicMin(anb + row, __float_as_int(n2));
      }
  }
}

// ---------------- Kernel C: multi-block deterministic loss -----------------
// 8 blocks x 1024 thr, 1 row/thread. Partial sums accumulate via int64
// fixed-point (x 2^22) atomicAdd — integer addition is order-independent, so
// the result is bit-deterministic across replays. Last block writes d_out.
__global__ __launch_bounds__(1024) void loss_kernel(
    const int* __restrict__ apb, const int* __restrict__ anb,
    unsigned long long* __restrict__ lsum, unsigned int* __restrict__ lcnt,
    float* __restrict__ out) {
  __shared__ float red[16];
  const int i = blockIdx.x * 1024 + threadIdx.x;
  float ap = sqrtf(__int_as_float(apb[i]));
  float an = sqrtf(__int_as_float(anb[i]));     // +inf sentinel -> relu(-inf)=0
  float li = ap - an + MARGIN_F;
  float s = li > 0.f ? li : 0.f;
  #pragma unroll
  for (int off = 32; off >= 1; off >>= 1) s += __shfl_xor(s, off);
  const int w = threadIdx.x >> 6, l = threadIdx.x & 63;
  if (l == 0) red[w] = s;
  __syncthreads();
  if (threadIdx.x < 16) {
    float v = red[threadIdx.x];
    #pragma unroll
    for (int off = 8; off >= 1; off >>= 1) v += __shfl_xor(v, off);
    if (threadIdx.x == 0) {
      unsigned long long q = (unsigned long long)(long long)((double)v * 4194304.0);
      atomicAdd(lsum, q);
      __threadfence();
      unsigned int old = atomicAdd(lcnt, 1u);
      if (old == gridDim.x - 1) {
        unsigned long long tot = atomicAdd(lsum, 0ull);
        out[0] = (float)((double)tot * (1.0 / 4194304.0) / (double)N_ROWS);
      }
    }
  }
}

extern "C" void kernel_launch(void* const* d_in, const int* in_sizes, int n_in,
                              void* d_out, int out_size, void* d_ws, size_t ws_size,
                              hipStream_t stream) {
  const float* x = (const float*)d_in[0];
  const int* tgt = (const int*)d_in[1];
  float* out = (float*)d_out;

  char* ws = (char*)d_ws;
  unsigned short* xbA = (unsigned short*)ws;                // 2 MB frag-major -2x
  unsigned short* xbBrow = (unsigned short*)(ws + 2097152); // 2 MB row-major x
  float2* meta = (float2*)(ws + 4194304);                   // 64 KB (sq, tgt)
  int* apb = (int*)(ws + 4259840);                          // 32 KB ap^2 bits
  int* anb = (int*)(ws + 4292608);                          // 32 KB an^2 bits
  unsigned long long* lsum = (unsigned long long*)(ws + 4325376);
  unsigned int* lcnt = (unsigned int*)(ws + 4325384);

  prep_kernel<<<2048, 256, 0, stream>>>(x, tgt, xbA, xbBrow, meta, apb, anb, lsum, lcnt);
  gram_mine_kernel<<<dim3(64, 8), 256, 0, stream>>>(xbA, xbBrow, meta, apb, anb);
  loss_kernel<<<8, 1024, 0, stream>>>(apb, anb, lsum, lcnt, out);
}